// Round 9
// baseline (22768.402 us; speedup 1.0000x reference)
//
#include <hip/hip_runtime.h>
#include <math.h>

#define S_LEN 4096
#define HID   2048
#define NBLK  256
#define NTHR  512   // 8 waves/block, 1 block/CU

typedef unsigned int       u32;
typedef unsigned long long u64;
typedef unsigned u32x4 __attribute__((ext_vector_type(4)));
typedef float v2f __attribute__((ext_vector_type(2)));

// R13 = R9/R12's proven sync (tags, exclusive lines, serial volley poll)
//  with the intra-block funnel removed:
//  - wave wv owns unit m=8b+wv: its 4 columns are the 4 gates of m. After
//    the butterfly reduce, lanes 0-3 apply one nonlinearity each in
//    parallel, 4 in-wave broadcasts, cx/hx replicated per-lane, lane 0
//    publishes IMMEDIATELY. No barrier B, no gates_lds, no serialized
//    8-unit tail. (R5 tried this mapping; its regression was cross-block
//    false-sharing + spec-sweep, both fixed since R9.)
//  - hx_lds double-buffered by parity: staging t+1 overwrites the buffer
//    last read at t-1; reaching the stage requires detection of all t+1
//    tags, which requires our own t-publishes, which postdate every t-1
//    read -> no WAR hazard, barrier A alone suffices.
//  - v2f-packed weights/hx -> v_pk_fma_f32 halves FMA issue (512->256cy).
//  - counter gate dropped (R12: only -1.4%, incompatible with per-wave
//    publish); setprio dropped (waves symmetric now).
//  Sync model (R4/R9/R11/R12 falsifications): detect latency is raw
//  publish-drain + ~1.5 coherent-RTT (~4000cy) -- insensitive to request
//  rate, poller population, pacing. This round attacks the ~2600cy
//  intra-block part instead.
//  Tag scheme unchanged (validated R6-R12): value with 2-LSB tag, want
//  ((t+1)&3)^2, parity half-lines of the block's exclusive 64B line,
//  0xAA poison (tag 2) unreachable by same-address monotonicity.

__device__ __forceinline__ float fast_sigmoid(float x) {
    float e = __builtin_amdgcn_exp2f(-1.44269504f * x);   // 2^(-x*log2e)
    return __builtin_amdgcn_rcpf(1.0f + e);
}

__global__ __launch_bounds__(NTHR, 2)
void qlstm_persistent(const float* __restrict__ inp,     // (S,1,4)
                      const float* __restrict__ conv_w,  // (4)
                      const float* __restrict__ conv_b,  // (1)
                      const float* __restrict__ Wg,      // (2049, 8192) row-major
                      const float* __restrict__ bg,      // (8192)
                      float* __restrict__ out,           // S*H + H + H
                      float* __restrict__ ws)            // scratch (poison 0xAA ok)
{
    const int b   = blockIdx.x;
    const int tid = threadIdx.x;
    const int l   = tid & 63;
    const int wv  = tid >> 6;

    u32* tbl = (u32*)ws;   // [NBLK][16]: exclusive 64B line per block
                           // words 0..7 = parity 0, 8..15 = parity 1

    __shared__ __align__(16) float hx_lds[2][HID];
    __shared__ __align__(16) float conv_lds[S_LEN];

    // ---------------- init phase ----------------
    {
        const float cw0 = conv_w[0], cw1 = conv_w[1], cw2 = conv_w[2], cw3 = conv_w[3];
        const float cb  = conv_b[0];
        for (int g = tid; g < S_LEN; g += NTHR) {
            float4 x = ((const float4*)inp)[g];
            float v = x.x*cw0 + x.y*cw1 + x.z*cw2 + x.w*cw3 + cb;
            conv_lds[g] = fast_sigmoid(v);
        }
    }
    // hx_0 = 0 lives purely in LDS: step 0 needs no global exchange.
    ((float4*)hx_lds[0])[tid] = make_float4(0.f, 0.f, 0.f, 0.f);

    const int m = b * 8 + wv;        // this wave's hidden unit

    // per-lane gate-column row-0 weight & bias (lanes 0..3 = gates f,i,g,o)
    float w0 = 0.f, bb = 0.f;
    if (l < 4) {
        int jc = (l << 11) + m;
        w0 = Wg[jc];
        bb = bg[jc];
    }

    // packed weights: wA[c][j] = rows 1+4l+256j+{0,1}, wB = +{2,3}, col c*2048+m
    v2f wA[4][8], wB[4][8];
    #pragma unroll
    for (int j = 0; j < 8; ++j) {
        const size_t row = (size_t)(1 + 4*l + 256*j);
        #pragma unroll
        for (int c = 0; c < 4; ++c) {
            const int jc = (c << 11) + m;
            v2f a, bv;
            a.x  = Wg[(row    ) * 8192 + jc];
            a.y  = Wg[(row + 1) * 8192 + jc];
            bv.x = Wg[(row + 2) * 8192 + jc];
            bv.y = Wg[(row + 3) * 8192 + jc];
            wA[c][j] = a;
            wB[c][j] = bv;
        }
    }

    float cx = 0.0f;                 // replicated across the wave's 64 lanes

    // thread tid polls units 4*tid..4*tid+3: block tid>>1, half (tid&1)
    const u32* poll_base = tbl + (tid >> 1) * 16 + (tid & 1) * 4;

    // ---------------- recurrence ----------------
    for (int t = 0; t < S_LEN; ++t) {
        if (t) {
            const u32 want = ((u32)(t + 1) & 3u) ^ 2u;
            const u32* pp = poll_base + ((t & 1) << 3);   // parity half-line
            u32x4 q;
            u32 miss;
            do {
                asm volatile("global_load_dwordx4 %0, %1, off sc0 sc1\n\t"
                             "s_waitcnt vmcnt(0)"
                             : "=v"(q) : "v"(pp) : "memory");
                miss = ((q[0] ^ want) & 3u) | ((q[1] ^ want) & 3u)
                     | ((q[2] ^ want) & 3u) | ((q[3] ^ want) & 3u);
            } while (miss);
            u32x4 st;
            st[0] = q[0] & ~3u; st[1] = q[1] & ~3u;
            st[2] = q[2] & ~3u; st[3] = q[3] & ~3u;
            ((u32x4*)hx_lds[t & 1])[tid] = st;   // ds_write_b128
        }
        __syncthreads();                         // A: hx_t staged (only barrier)

        // ---- 2048-MAC dot for the 4 gates of unit m (packed f32 FMA) ----
        const float4* hl = (const float4*)hx_lds[t & 1];
        v2f a0, a1, a2, a3;
        a0 = 0.f; a1 = 0.f; a2 = 0.f; a3 = 0.f;
        #pragma unroll
        for (int j = 0; j < 8; ++j) {
            float4 h = hl[l + 64*j];             // ds_read_b128, conflict-free
            v2f h01; h01.x = h.x; h01.y = h.y;
            v2f h23; h23.x = h.z; h23.y = h.w;
            a0 += h01 * wA[0][j];  a0 += h23 * wB[0][j];
            a1 += h01 * wA[1][j];  a1 += h23 * wB[1][j];
            a2 += h01 * wA[2][j];  a2 += h23 * wB[2][j];
            a3 += h01 * wA[3][j];  a3 += h23 * wB[3][j];
        }
        float s0 = a0.x + a0.y;
        float s1 = a1.x + a1.y;
        float s2 = a2.x + a2.y;
        float s3 = a3.x + a3.y;
        #pragma unroll
        for (int off = 1; off < 64; off <<= 1) {
            s0 += __shfl_xor(s0, off, 64);
            s1 += __shfl_xor(s1, off, 64);
            s2 += __shfl_xor(s2, off, 64);
            s3 += __shfl_xor(s3, off, 64);
        }

        // lane c owns gate c; gate 2 (update) is tanh = 2*sigmoid(2x)-1
        float a = s0;
        a = (l == 1) ? s1 : a;
        a = (l == 2) ? s2 : a;
        a = (l == 3) ? s3 : a;
        float ct = conv_lds[t];
        float x  = a + fmaf(ct, w0, bb);
        float xs = (l == 2) ? 2.0f * x : x;
        float y  = fast_sigmoid(xs);
        float g  = (l == 2) ? 2.0f * y - 1.0f : y;

        float f  = __shfl(g, 0, 64);
        float ii = __shfl(g, 1, 64);
        float gg = __shfl(g, 2, 64);
        float o  = __shfl(g, 3, 64);
        cx = f * cx + ii * gg;                            // identical on all lanes
        float hx = o * (2.0f * fast_sigmoid(2.0f * cx) - 1.0f);

        if (l == 0) {
            // publish hx_{t+1}[m] into parity (t+1)&1 of the block's OWN line
            u32 word = (__float_as_uint(hx) & ~3u) | (((u32)(t + 2) & 3u) ^ 2u);
            __hip_atomic_store(tbl + b*16 + (((t + 1) & 1) << 3) + wv, word,
                               __ATOMIC_RELAXED, __HIP_MEMORY_SCOPE_AGENT);
            out[(size_t)t * HID + m] = hx;
            if (t == S_LEN - 1) {
                out[(size_t)S_LEN * HID + m]       = hx;   // final hx
                out[(size_t)S_LEN * HID + HID + m] = cx;   // final cx
            }
        }
    }
}

extern "C" void kernel_launch(void* const* d_in, const int* in_sizes, int n_in,
                              void* d_out, int out_size, void* d_ws, size_t ws_size,
                              hipStream_t stream) {
    const float* inp    = (const float*)d_in[0];
    const float* conv_w = (const float*)d_in[1];
    const float* conv_b = (const float*)d_in[2];
    const float* Wg     = (const float*)d_in[3];
    const float* bg     = (const float*)d_in[4];
    float* out = (float*)d_out;
    float* ws  = (float*)d_ws;

    // no memset needed: poison tag (0xAA..&3 == 2) only aliases parity-1's
    // t=3 want; every parity-1 word was genuinely written at t=0 (tag 0) and
    // t=2 (tag 2) first, and same-address coherence is monotonic.
    void* args[] = {(void*)&inp, (void*)&conv_w, (void*)&conv_b,
                    (void*)&Wg, (void*)&bg, (void*)&out, (void*)&ws};
    hipLaunchCooperativeKernel((void*)qlstm_persistent,
                               dim3(NBLK), dim3(NTHR), args, 0, stream);
}

// Round 10
// 11132.012 us; speedup vs baseline: 2.0453x; 2.0453x over previous
//
#include <hip/hip_runtime.h>
#include <math.h>

#define S_LEN 4096
#define HID   2048
#define NBLK  256
#define NTHR  512   // 8 waves/block, 1 block/CU

typedef unsigned int       u32;
typedef unsigned long long u64;
typedef unsigned u32x4 __attribute__((ext_vector_type(4)));

// R14 = R12 (best, 11.29ms) + amdgpu_waves_per_eu(2,2). Reframed model:
//  weights are NOT register-resident (VGPR 88-116 all rounds) -> every step
//  re-streams 64MB chip-wide (8MB/XCD vs 4MB L2) at ~23TB/s = the step time.
//  This explains every sync-path null result (R9/R11/R12: +-2%): sync was
//  never binding. R8's AGPR "falsification" was confounded (FETCH stayed
//  528MB = stream persisted; 128 serial asm reads added ~1600cy VALU).
//  __launch_bounds__ only sets MIN waves/EU; the allocator aims higher
//  (96-116 VGPR tiers) and sinks the weight loads into the loop. The
//  attribute's MAX=2 waves/EU grants 256 VGPR/wave -> LICM hoists the 128
//  loop-invariant loads naturally. Occupancy unchanged (already 2/EU).
//  Diagnostics: VGPR >=180 & FETCH <200MB = resident; dur then reveals
//  whether the weight stream (drop to ~7ms) or sync RTT (flat) was binding.
//  R13 reverted (per-wave 4B publishes: WRITE 295MB, FETCH 1.5GB — partial-
//  line RMW amplification; coalesced single-wave publish is mandatory).
//  Everything else identical to R12: counter gate (wave7 polls 8 counters,
//  rest spin on LDS), one-shot tag-verified volley, value-with-2-LSB-tag
//  entries, exclusive 64B line per block, coalesced 32B publish, fast exp2
//  sigmoid/tanh, setprio around tail, conv precompute, hx_0 prestaged.

__device__ __forceinline__ float fast_sigmoid(float x) {
    float e = __builtin_amdgcn_exp2f(-1.44269504f * x);   // 2^(-x*log2e)
    return __builtin_amdgcn_rcpf(1.0f + e);
}

__global__ __launch_bounds__(NTHR)
__attribute__((amdgpu_waves_per_eu(2, 2)))
void qlstm_persistent(const float* __restrict__ inp,     // (S,1,4)
                      const float* __restrict__ conv_w,  // (4)
                      const float* __restrict__ conv_b,  // (1)
                      const float* __restrict__ Wg,      // (2049, 8192) row-major
                      const float* __restrict__ bg,      // (8192)
                      float* __restrict__ out,           // S*H + H + H
                      float* __restrict__ ws)            // scratch (poison 0xAA ok)
{
    const int b   = blockIdx.x;
    const int tid = threadIdx.x;
    const int l   = tid & 63;
    const int wv  = tid >> 6;

    u32* tbl = (u32*)ws;            // [NBLK][16]: exclusive 64B line per block
    u32* cnt = (u32*)ws + 4096;     // 8 counters, 64B apart (own lines)

    __shared__ __align__(16) float hx_lds[HID];
    __shared__ __align__(16) float conv_lds[S_LEN];
    __shared__ float gates_lds[32];
    __shared__ float colw0[32];
    __shared__ float colb[32];
    __shared__ u32 goflag;

    // ---------------- init phase ----------------
    {
        const float cw0 = conv_w[0], cw1 = conv_w[1], cw2 = conv_w[2], cw3 = conv_w[3];
        const float cb  = conv_b[0];
        for (int g = tid; g < S_LEN; g += NTHR) {
            float4 x = ((const float4*)inp)[g];
            float v = x.x*cw0 + x.y*cw1 + x.z*cw2 + x.w*cw3 + cb;
            conv_lds[g] = fast_sigmoid(v);
        }
    }
    // hx_0 = 0 lives purely in LDS: step 0 needs no global exchange at all.
    ((float4*)hx_lds)[tid] = make_float4(0.f, 0.f, 0.f, 0.f);
    if (tid == 0) goflag = 1u;                   // < 2: first gated iter spins
    if (b < 8 && tid == 0)                        // counter init (see header)
        __hip_atomic_store(&cnt[b * 16], 0u,
                           __ATOMIC_RELAXED, __HIP_MEMORY_SCOPE_AGENT);

    // this wave's 4 global column indices
    int jcol[4];
    #pragma unroll
    for (int c = 0; c < 4; ++c) {
        int cgi  = 4*wv + c;
        int gate = cgi >> 3;
        int mi   = cgi & 7;
        jcol[c]  = (gate << 11) + (b * 8 + mi);     // gate*2048 + m
    }
    if (l == 0) {
        #pragma unroll
        for (int c = 0; c < 4; ++c) {
            int cgi = 4*wv + c;
            colw0[cgi] = Wg[jcol[c]];               // row 0 = input (c_t) weight
            colb[cgi]  = bg[jcol[c]];
        }
    }

    // W registers: wreg[c][4j+r] = W[1 + 4l + 256j + r][jcol[c]]
    // With waves_per_eu(2,2) the allocator has 256 VGPR/wave: these 128
    // loop-invariant loads should be hoisted and stay resident.
    float wreg[4][32];
    #pragma unroll
    for (int j = 0; j < 8; ++j)
        #pragma unroll
        for (int r = 0; r < 4; ++r) {
            const float* rowp = Wg + (size_t)(1 + 4*l + 256*j + r) * 8192;
            #pragma unroll
            for (int c = 0; c < 4; ++c)
                wreg[c][4*j + r] = rowp[jcol[c]];
        }

    float cx = 0.0f;                    // live only in lanes tid<8
    const int m_out = b * 8 + tid;      // hidden index for tid<8

    // thread tid polls units 4*tid..4*tid+3: block tid>>1, units (tid&1)*4+k
    const u32* poll_base = tbl + (tid >> 1) * 16 + (tid & 1) * 4;
    u32* pub_base = tbl + b * 16 + tid;      // + parity*8 at publish (tid<8)

    // ---------------- recurrence ----------------
    for (int t = 0; t < S_LEN; ++t) {
        if (t) {
            // ---- gate (t>=2): wave 7 polls 8 counters; rest spin on LDS ----
            if (t >= 2) {
                const u32 tgt = 32u * (u32)(t - 1);
                if (wv == 7) {
                    u32 c;
                    do {
                        c = tgt;
                        if (l < 8)
                            c = __hip_atomic_load(&cnt[l * 16], __ATOMIC_RELAXED,
                                                  __HIP_MEMORY_SCOPE_AGENT);
                    } while (!__all(c >= tgt));
                    if (l == 0)
                        __hip_atomic_store(&goflag, (u32)t, __ATOMIC_RELAXED,
                                           __HIP_MEMORY_SCOPE_WORKGROUP);
                } else {
                    while (__hip_atomic_load(&goflag, __ATOMIC_RELAXED,
                                             __HIP_MEMORY_SCOPE_WORKGROUP) < (u32)t) {}
                }
            }

            // ---- one-shot tag-verified volley (retries rare after gate) ----
            const u32 want = ((u32)(t + 1) & 3u) ^ 2u;
            const u32* pp = poll_base + ((t & 1) << 3);   // parity half-line
            u32x4 q;
            u32 miss;
            do {
                asm volatile("global_load_dwordx4 %0, %1, off sc0 sc1\n\t"
                             "s_waitcnt vmcnt(0)"
                             : "=v"(q) : "v"(pp) : "memory");
                miss = ((q[0] ^ want) & 3u) | ((q[1] ^ want) & 3u)
                     | ((q[2] ^ want) & 3u) | ((q[3] ^ want) & 3u);
            } while (miss);
            u32x4 st;
            st[0] = q[0] & ~3u; st[1] = q[1] & ~3u;
            st[2] = q[2] & ~3u; st[3] = q[3] & ~3u;
            ((u32x4*)hx_lds)[tid] = st;     // units 4*tid..+3, ds_write_b128
        }
        __syncthreads();                    // A: hx_t staged

        // ---- 2048-MAC dot for this wave's 4 gate columns ----
        const float4* hl = (const float4*)hx_lds;
        float acc0 = 0.f, acc1 = 0.f, acc2 = 0.f, acc3 = 0.f;
        #pragma unroll
        for (int j = 0; j < 8; ++j) {
            float4 h = hl[l + 64*j];        // ds_read_b128, conflict-free
            acc0 = fmaf(h.x, wreg[0][4*j+0], acc0);
            acc1 = fmaf(h.x, wreg[1][4*j+0], acc1);
            acc2 = fmaf(h.x, wreg[2][4*j+0], acc2);
            acc3 = fmaf(h.x, wreg[3][4*j+0], acc3);
            acc0 = fmaf(h.y, wreg[0][4*j+1], acc0);
            acc1 = fmaf(h.y, wreg[1][4*j+1], acc1);
            acc2 = fmaf(h.y, wreg[2][4*j+1], acc2);
            acc3 = fmaf(h.y, wreg[3][4*j+1], acc3);
            acc0 = fmaf(h.z, wreg[0][4*j+2], acc0);
            acc1 = fmaf(h.z, wreg[1][4*j+2], acc1);
            acc2 = fmaf(h.z, wreg[2][4*j+2], acc2);
            acc3 = fmaf(h.z, wreg[3][4*j+2], acc3);
            acc0 = fmaf(h.w, wreg[0][4*j+3], acc0);
            acc1 = fmaf(h.w, wreg[1][4*j+3], acc1);
            acc2 = fmaf(h.w, wreg[2][4*j+3], acc2);
            acc3 = fmaf(h.w, wreg[3][4*j+3], acc3);
        }
        #pragma unroll
        for (int off = 32; off; off >>= 1) {
            acc0 += __shfl_down(acc0, off, 64);
            acc1 += __shfl_down(acc1, off, 64);
            acc2 += __shfl_down(acc2, off, 64);
            acc3 += __shfl_down(acc3, off, 64);
        }
        if (l == 0) {
            gates_lds[4*wv + 0] = acc0;
            gates_lds[4*wv + 1] = acc1;
            gates_lds[4*wv + 2] = acc2;
            gates_lds[4*wv + 3] = acc3;
        }
        __syncthreads();                    // B: gates complete

        if (wv == 0) __builtin_amdgcn_s_setprio(1);   // publisher outranks spinners
        if (tid < 8) {
            float ct = conv_lds[t];
            float fg = gates_lds[tid]      + ct*colw0[tid]      + colb[tid];
            float ig = gates_lds[8 + tid]  + ct*colw0[8 + tid]  + colb[8 + tid];
            float gg = gates_lds[16 + tid] + ct*colw0[16 + tid] + colb[16 + tid];
            float og = gates_lds[24 + tid] + ct*colw0[24 + tid] + colb[24 + tid];
            float f  = fast_sigmoid(fg);
            float ii = fast_sigmoid(ig);
            float gv = 2.0f * fast_sigmoid(2.0f * gg) - 1.0f;   // tanh
            float o  = fast_sigmoid(og);
            cx = f * cx + ii * gv;
            float hx = o * (2.0f * fast_sigmoid(2.0f * cx) - 1.0f);
            // publish hx_{t+1} into parity (t+1)&1 of the block's OWN line:
            // 8 lanes -> one 32B store, line never shared with another block.
            u32 word = (__float_as_uint(hx) & ~3u) | (((u32)(t + 2) & 3u) ^ 2u);
            __hip_atomic_store(pub_base + (((t + 1) & 1) << 3), word,
                               __ATOMIC_RELAXED, __HIP_MEMORY_SCOPE_AGENT);
            // counter bump: after the tag store in program order.
            if (tid == 0)
                __hip_atomic_fetch_add(&cnt[(b >> 5) * 16], 1u,
                                       __ATOMIC_RELAXED, __HIP_MEMORY_SCOPE_AGENT);
            out[(size_t)t * HID + m_out] = hx;
            if (t == S_LEN - 1) {
                out[(size_t)S_LEN * HID + m_out]       = hx;   // final hx
                out[(size_t)S_LEN * HID + HID + m_out] = cx;   // final cx
            }
        }
        if (wv == 0) __builtin_amdgcn_s_setprio(0);
    }
}

extern "C" void kernel_launch(void* const* d_in, const int* in_sizes, int n_in,
                              void* d_out, int out_size, void* d_ws, size_t ws_size,
                              hipStream_t stream) {
    const float* inp    = (const float*)d_in[0];
    const float* conv_w = (const float*)d_in[1];
    const float* conv_b = (const float*)d_in[2];
    const float* Wg     = (const float*)d_in[3];
    const float* bg     = (const float*)d_in[4];
    float* out = (float*)d_out;
    float* ws  = (float*)d_ws;

    // no memset needed: tag poison unreachable (R9 proof); counters are
    // kernel-initialized by blocks 0-7 before any add can occur.
    void* args[] = {(void*)&inp, (void*)&conv_w, (void*)&conv_b,
                    (void*)&Wg, (void*)&bg, (void*)&out, (void*)&ws};
    hipLaunchCooperativeKernel((void*)qlstm_persistent,
                               dim3(NBLK), dim3(NTHR), args, 0, stream);
}

// Round 11
// 11042.643 us; speedup vs baseline: 2.0619x; 1.0081x over previous
//
#include <hip/hip_runtime.h>
#include <math.h>

#define S_LEN 4096
#define HID   2048
#define NBLK  256
#define NTHR  512   // 8 waves/block, 1 block/CU

typedef unsigned int       u32;
typedef unsigned long long u64;
typedef unsigned u32x4 __attribute__((ext_vector_type(4)));

// R15 = R14 + R7's per-element "+v" pin. The combination is the experiment:
//  - R7: pin forced materialization but SPILLED (budget stuck at ~100-reg
//    tier -> scratch traffic, FETCH rose).
//  - R14: waves_per_eu(2,2) granted 256 VGPR/wave but forced nothing
//    (VGPR_Count still 88 -> loads still sunk into the loop).
//  Model (prices correctly for the first time): per step 64MB of weights
//  stream chip-wide; per XCD 8MB vs 4MB L2 -> ~32MB/step refills from L3
//  at ~10-14TB/s ~= 2.5-3us = the observed 2.72us step. This is why every
//  sync-path intervention (rate/population/pacing/gate, R9-R14) was +-2%:
//  the L3->L2 weight refill is the floor underneath them all.
//  With pin+budget: 128 pinned + ~80 working ~= 210 <= 256 -> no spill,
//  weights read once, the L3 stream disappears.
//  Diagnostics: VGPR>=200 & FETCH<150MB = resident. dur then splits the
//  model: ~7ms = weight stream was binding; flat ~11ms = sync RTT floor
//  (roofline argument next, from a clean position).
//  Everything else identical to R14/R12 (best): counter gate, tag-verified
//  volley poll, value-with-2-LSB-tag entries, exclusive 64B line per block,
//  coalesced 32B publish, fast exp2 sigmoid/tanh, setprio, conv precompute.

__device__ __forceinline__ float fast_sigmoid(float x) {
    float e = __builtin_amdgcn_exp2f(-1.44269504f * x);   // 2^(-x*log2e)
    return __builtin_amdgcn_rcpf(1.0f + e);
}

__global__ __launch_bounds__(NTHR)
__attribute__((amdgpu_waves_per_eu(2, 2)))
void qlstm_persistent(const float* __restrict__ inp,     // (S,1,4)
                      const float* __restrict__ conv_w,  // (4)
                      const float* __restrict__ conv_b,  // (1)
                      const float* __restrict__ Wg,      // (2049, 8192) row-major
                      const float* __restrict__ bg,      // (8192)
                      float* __restrict__ out,           // S*H + H + H
                      float* __restrict__ ws)            // scratch (poison 0xAA ok)
{
    const int b   = blockIdx.x;
    const int tid = threadIdx.x;
    const int l   = tid & 63;
    const int wv  = tid >> 6;

    u32* tbl = (u32*)ws;            // [NBLK][16]: exclusive 64B line per block
    u32* cnt = (u32*)ws + 4096;     // 8 counters, 64B apart (own lines)

    __shared__ __align__(16) float hx_lds[HID];
    __shared__ __align__(16) float conv_lds[S_LEN];
    __shared__ float gates_lds[32];
    __shared__ float colw0[32];
    __shared__ float colb[32];
    __shared__ u32 goflag;

    // ---------------- init phase ----------------
    {
        const float cw0 = conv_w[0], cw1 = conv_w[1], cw2 = conv_w[2], cw3 = conv_w[3];
        const float cb  = conv_b[0];
        for (int g = tid; g < S_LEN; g += NTHR) {
            float4 x = ((const float4*)inp)[g];
            float v = x.x*cw0 + x.y*cw1 + x.z*cw2 + x.w*cw3 + cb;
            conv_lds[g] = fast_sigmoid(v);
        }
    }
    // hx_0 = 0 lives purely in LDS: step 0 needs no global exchange at all.
    ((float4*)hx_lds)[tid] = make_float4(0.f, 0.f, 0.f, 0.f);
    if (tid == 0) goflag = 1u;                   // < 2: first gated iter spins
    if (b < 8 && tid == 0)                        // counter init (see header)
        __hip_atomic_store(&cnt[b * 16], 0u,
                           __ATOMIC_RELAXED, __HIP_MEMORY_SCOPE_AGENT);

    // this wave's 4 global column indices
    int jcol[4];
    #pragma unroll
    for (int c = 0; c < 4; ++c) {
        int cgi  = 4*wv + c;
        int gate = cgi >> 3;
        int mi   = cgi & 7;
        jcol[c]  = (gate << 11) + (b * 8 + mi);     // gate*2048 + m
    }
    if (l == 0) {
        #pragma unroll
        for (int c = 0; c < 4; ++c) {
            int cgi = 4*wv + c;
            colw0[cgi] = Wg[jcol[c]];               // row 0 = input (c_t) weight
            colb[cgi]  = bg[jcol[c]];
        }
    }

    // W registers: wreg[c][4j+r] = W[1 + 4l + 256j + r][jcol[c]]
    float wreg[4][32];
    #pragma unroll
    for (int j = 0; j < 8; ++j)
        #pragma unroll
        for (int r = 0; r < 4; ++r) {
            const float* rowp = Wg + (size_t)(1 + 4*l + 256*j + r) * 8192;
            #pragma unroll
            for (int c = 0; c < 4; ++c)
                wreg[c][4*j + r] = rowp[jcol[c]];
        }
    // PIN: each weight becomes the output of a volatile asm -> the load
    // cannot be rematerialized inside the loop. With waves_per_eu(2,2)
    // granting 256 VGPR/wave, the 128 pinned values fit without spilling
    // (R7's failure mode). This is the pin+budget combination.
    #pragma unroll
    for (int c = 0; c < 4; ++c)
        #pragma unroll
        for (int k = 0; k < 32; ++k)
            asm volatile("" : "+v"(wreg[c][k]));

    float cx = 0.0f;                    // live only in lanes tid<8
    const int m_out = b * 8 + tid;      // hidden index for tid<8

    // thread tid polls units 4*tid..4*tid+3: block tid>>1, units (tid&1)*4+k
    const u32* poll_base = tbl + (tid >> 1) * 16 + (tid & 1) * 4;
    u32* pub_base = tbl + b * 16 + tid;      // + parity*8 at publish (tid<8)

    // ---------------- recurrence ----------------
    for (int t = 0; t < S_LEN; ++t) {
        if (t) {
            // ---- gate (t>=2): wave 7 polls 8 counters; rest spin on LDS ----
            if (t >= 2) {
                const u32 tgt = 32u * (u32)(t - 1);
                if (wv == 7) {
                    u32 c;
                    do {
                        c = tgt;
                        if (l < 8)
                            c = __hip_atomic_load(&cnt[l * 16], __ATOMIC_RELAXED,
                                                  __HIP_MEMORY_SCOPE_AGENT);
                    } while (!__all(c >= tgt));
                    if (l == 0)
                        __hip_atomic_store(&goflag, (u32)t, __ATOMIC_RELAXED,
                                           __HIP_MEMORY_SCOPE_WORKGROUP);
                } else {
                    while (__hip_atomic_load(&goflag, __ATOMIC_RELAXED,
                                             __HIP_MEMORY_SCOPE_WORKGROUP) < (u32)t) {}
                }
            }

            // ---- one-shot tag-verified volley (retries rare after gate) ----
            const u32 want = ((u32)(t + 1) & 3u) ^ 2u;
            const u32* pp = poll_base + ((t & 1) << 3);   // parity half-line
            u32x4 q;
            u32 miss;
            do {
                asm volatile("global_load_dwordx4 %0, %1, off sc0 sc1\n\t"
                             "s_waitcnt vmcnt(0)"
                             : "=v"(q) : "v"(pp) : "memory");
                miss = ((q[0] ^ want) & 3u) | ((q[1] ^ want) & 3u)
                     | ((q[2] ^ want) & 3u) | ((q[3] ^ want) & 3u);
            } while (miss);
            u32x4 st;
            st[0] = q[0] & ~3u; st[1] = q[1] & ~3u;
            st[2] = q[2] & ~3u; st[3] = q[3] & ~3u;
            ((u32x4*)hx_lds)[tid] = st;     // units 4*tid..+3, ds_write_b128
        }
        __syncthreads();                    // A: hx_t staged

        // ---- 2048-MAC dot for this wave's 4 gate columns ----
        const float4* hl = (const float4*)hx_lds;
        float acc0 = 0.f, acc1 = 0.f, acc2 = 0.f, acc3 = 0.f;
        #pragma unroll
        for (int j = 0; j < 8; ++j) {
            float4 h = hl[l + 64*j];        // ds_read_b128, conflict-free
            acc0 = fmaf(h.x, wreg[0][4*j+0], acc0);
            acc1 = fmaf(h.x, wreg[1][4*j+0], acc1);
            acc2 = fmaf(h.x, wreg[2][4*j+0], acc2);
            acc3 = fmaf(h.x, wreg[3][4*j+0], acc3);
            acc0 = fmaf(h.y, wreg[0][4*j+1], acc0);
            acc1 = fmaf(h.y, wreg[1][4*j+1], acc1);
            acc2 = fmaf(h.y, wreg[2][4*j+1], acc2);
            acc3 = fmaf(h.y, wreg[3][4*j+1], acc3);
            acc0 = fmaf(h.z, wreg[0][4*j+2], acc0);
            acc1 = fmaf(h.z, wreg[1][4*j+2], acc1);
            acc2 = fmaf(h.z, wreg[2][4*j+2], acc2);
            acc3 = fmaf(h.z, wreg[3][4*j+2], acc3);
            acc0 = fmaf(h.w, wreg[0][4*j+3], acc0);
            acc1 = fmaf(h.w, wreg[1][4*j+3], acc1);
            acc2 = fmaf(h.w, wreg[2][4*j+3], acc2);
            acc3 = fmaf(h.w, wreg[3][4*j+3], acc3);
        }
        #pragma unroll
        for (int off = 32; off; off >>= 1) {
            acc0 += __shfl_down(acc0, off, 64);
            acc1 += __shfl_down(acc1, off, 64);
            acc2 += __shfl_down(acc2, off, 64);
            acc3 += __shfl_down(acc3, off, 64);
        }
        if (l == 0) {
            gates_lds[4*wv + 0] = acc0;
            gates_lds[4*wv + 1] = acc1;
            gates_lds[4*wv + 2] = acc2;
            gates_lds[4*wv + 3] = acc3;
        }
        __syncthreads();                    // B: gates complete

        if (wv == 0) __builtin_amdgcn_s_setprio(1);   // publisher outranks spinners
        if (tid < 8) {
            float ct = conv_lds[t];
            float fg = gates_lds[tid]      + ct*colw0[tid]      + colb[tid];
            float ig = gates_lds[8 + tid]  + ct*colw0[8 + tid]  + colb[8 + tid];
            float gg = gates_lds[16 + tid] + ct*colw0[16 + tid] + colb[16 + tid];
            float og = gates_lds[24 + tid] + ct*colw0[24 + tid] + colb[24 + tid];
            float f  = fast_sigmoid(fg);
            float ii = fast_sigmoid(ig);
            float gv = 2.0f * fast_sigmoid(2.0f * gg) - 1.0f;   // tanh
            float o  = fast_sigmoid(og);
            cx = f * cx + ii * gv;
            float hx = o * (2.0f * fast_sigmoid(2.0f * cx) - 1.0f);
            // publish hx_{t+1} into parity (t+1)&1 of the block's OWN line:
            // 8 lanes -> one 32B store, line never shared with another block.
            u32 word = (__float_as_uint(hx) & ~3u) | (((u32)(t + 2) & 3u) ^ 2u);
            __hip_atomic_store(pub_base + (((t + 1) & 1) << 3), word,
                               __ATOMIC_RELAXED, __HIP_MEMORY_SCOPE_AGENT);
            // counter bump: after the tag store in program order.
            if (tid == 0)
                __hip_atomic_fetch_add(&cnt[(b >> 5) * 16], 1u,
                                       __ATOMIC_RELAXED, __HIP_MEMORY_SCOPE_AGENT);
            out[(size_t)t * HID + m_out] = hx;
            if (t == S_LEN - 1) {
                out[(size_t)S_LEN * HID + m_out]       = hx;   // final hx
                out[(size_t)S_LEN * HID + HID + m_out] = cx;   // final cx
            }
        }
        if (wv == 0) __builtin_amdgcn_s_setprio(0);
    }
}

extern "C" void kernel_launch(void* const* d_in, const int* in_sizes, int n_in,
                              void* d_out, int out_size, void* d_ws, size_t ws_size,
                              hipStream_t stream) {
    const float* inp    = (const float*)d_in[0];
    const float* conv_w = (const float*)d_in[1];
    const float* conv_b = (const float*)d_in[2];
    const float* Wg     = (const float*)d_in[3];
    const float* bg     = (const float*)d_in[4];
    float* out = (float*)d_out;
    float* ws  = (float*)d_ws;

    // no memset needed: tag poison unreachable (R9 proof); counters are
    // kernel-initialized by blocks 0-7 before any add can occur.
    void* args[] = {(void*)&inp, (void*)&conv_w, (void*)&conv_b,
                    (void*)&Wg, (void*)&bg, (void*)&out, (void*)&ws};
    hipLaunchCooperativeKernel((void*)qlstm_persistent,
                               dim3(NBLK), dim3(NTHR), args, 0, stream);
}